// Round 19
// baseline (35.417 us; speedup 1.0000x reference)
//
#include <hip/hip_runtime.h>
#include <hip/hip_bf16.h>

#define D_DIM 256
#define K_CODES 1024
#define N_ROWS (32 * 1024)
#define BLOCK_ROWS 64                 // rows per block (shared by 4 kq waves)
#define NBLK (N_ROWS / BLOCK_ROWS)    // 512 blocks -> 2/CU

typedef __attribute__((ext_vector_type(4))) float f32x4;
typedef __attribute__((ext_vector_type(2))) long i64x2;
typedef long i64;

#define MFMA8 __builtin_amdgcn_mfma_f32_16x16x32_fp8_fp8
#define CVT8 __builtin_amdgcn_cvt_pk_fp8_f32

static __device__ __forceinline__ void gload_lds16(const void* g, void* s) {
    __builtin_amdgcn_global_load_lds(
        (const __attribute__((address_space(1))) void*)g,
        (__attribute__((address_space(3))) void*)s, 16, 0, 0);
}

static __device__ __forceinline__ i64 pack_fp8x8(float4 p, float4 q, float S) {
    int w0 = CVT8(p.x * S, p.y * S, 0, false);
    w0     = CVT8(p.z * S, p.w * S, w0, true);
    int w1 = CVT8(q.x * S, q.y * S, 0, false);
    w1     = CVT8(q.z * S, q.w * S, w1, true);
    return ((i64)(unsigned)w1 << 32) | (unsigned)w0;
}

// ---------------------------------------------------------------- prep
// (a) enorm1[k] = 1 + ||E[k]||^2 (keeps min-keys positive);
// (b) Eb8 = fp8(-1024*E), B-frag order, kk-PAIRED:
//     i64 idx(t16,kk,l) = t16*512 + (kk>>1)*128 + l*2 + (kk&1)
__global__ __launch_bounds__(256) void vq_prep(const float* __restrict__ E,
                                               float* __restrict__ enorm1,
                                               i64* __restrict__ Eb8) {
    int wave = threadIdx.x >> 6;
    int lane = threadIdx.x & 63;
    int k = blockIdx.x * 4 + wave;               // [0,1024)
    const float4 v = *reinterpret_cast<const float4*>(E + k * D_DIM + lane * 4);
    float s = v.x * v.x + v.y * v.y + v.z * v.z + v.w * v.w;
    #pragma unroll
    for (int off = 32; off; off >>= 1) s += __shfl_xor(s, off, 64);
    if (lane == 0) enorm1[k] = 1.0f + s;

    if (blockIdx.x < 128) {
        int g = blockIdx.x * 256 + threadIdx.x;  // [0, 32768)
        int t = g >> 9;
        int kk = (g >> 6) & 7;
        int l = g & 63;
        int code = t * 16 + (l & 15);
        int d0 = kk * 32 + ((l >> 4) << 3);
        const float* src = E + (size_t)code * D_DIM + d0;
        float4 v0 = *reinterpret_cast<const float4*>(src);
        float4 v1 = *reinterpret_cast<const float4*>(src + 4);
        Eb8[t * 512 + ((kk >> 1) << 7) + l * 2 + (kk & 1)] =
            pack_fp8x8(v0, v1, -1024.0f);
    }
}

// ---------------------------------------------------------------- main
// 512 blocks (2/CU, 8 waves/CU) x 256 thr. Wave kq: ALL 64 block rows
// (4 MFMA rowsets, A in regs) x codes [kq*256,+256) in 8 chunks of 32
// codes loaded DIRECTLY to registers (named bA/bB even/odd pipeline ->
// static regs, WAR-bounded hoisting). NO barriers / NO LDS in the sweep.
// Packed-key argmin (bits(1+|e|^2-2xe)|idx, fminf); 4-way kq merge at
// end = 3 fminf/row. X staged coalesced once (1 DMA/row, XOR chunk
// swizzle), packed to fp8 A-frags. Fused epilogue: gather f32 E (exact),
// loss via |x-q|^2 = minval + |x|^2.
__global__ __launch_bounds__(256, 2) void vq_main(const float* __restrict__ X,
                                                  const float* __restrict__ E,
                                                  const float* __restrict__ enorm1,
                                                  const i64* __restrict__ Eb8,
                                                  float* __restrict__ outq,
                                                  float* __restrict__ lpart) {
    __shared__ i64   Xs[8192];         // 64 KB: 64 rows x 1KB
    __shared__ float En1[1024];        // 4 KB
    __shared__ float fk[4][BLOCK_ROWS];
    __shared__ float fxn[BLOCK_ROWS];

    const int tid = threadIdx.x;
    const int kq  = tid >> 6;     // wave = code quarter
    const int l   = tid & 63;
    const int lr  = l & 15;
    const int lk  = l >> 4;
    const int brow = blockIdx.x * BLOCK_ROWS;

    // ---- stage X coalesced (wave kq stages rows [kq*16,+16)) + En quarter
    #pragma unroll
    for (int rr = 0; rr < 16; ++rr) {
        const int r = kq * 16 + rr;
        gload_lds16(X + (size_t)(brow + r) * D_DIM + (l ^ (r & 7)) * 4,
                    &Xs[r * 128]);
    }
    gload_lds16(enorm1 + kq * 256 + l * 4, &En1[kq * 256]);
    __syncthreads();   // drains vmcnt: all 64 rows + En landed

    // ---- B chunk loads (32 codes = 2 16-code tiles) into named registers
    i64x2 bA[2][4], bB[2][4];
#define LOADC(REG, C)                                                         \
    do {                                                                      \
        const i64* tb = Eb8 + ((size_t)kq * 16 + (C) * 2) * 512;              \
        _Pragma("unroll")                                                     \
        for (int p = 0; p < 4; ++p) {                                         \
            REG[0][p] = *reinterpret_cast<const i64x2*>(tb + p * 128 + l * 2);\
            REG[1][p] = *reinterpret_cast<const i64x2*>(tb + 512 + p * 128 + l * 2); \
        }                                                                     \
    } while (0)

    LOADC(bA, 0);      // in flight under the pack phase
    LOADC(bB, 1);

    // ---- pack ALL 64 rows -> fp8 A-frags (4 rowsets) + row norms
    const float* Xf = reinterpret_cast<const float*>(Xs);
    i64   a[4][8];
    float xn[4];
    #pragma unroll
    for (int s = 0; s < 4; ++s) {
        const int r = s * 16 + lr;
        float t = 0.0f;
        #pragma unroll
        for (int kk = 0; kk < 8; ++kk) {
            const int c0 = (kk * 8 + lk * 2) ^ (r & 7);
            const int c1 = (kk * 8 + lk * 2 + 1) ^ (r & 7);
            float4 p = *reinterpret_cast<const float4*>(&Xf[r * 256 + c0 * 4]);
            float4 q = *reinterpret_cast<const float4*>(&Xf[r * 256 + c1 * 4]);
            t += p.x * p.x + p.y * p.y + p.z * p.z + p.w * p.w
               + q.x * q.x + q.y * q.y + q.z * q.z + q.w * q.w;
            a[s][kk] = pack_fp8x8(p, q, 1.0f);
        }
        t += __shfl_xor(t, 16, 64);
        t += __shfl_xor(t, 32, 64);   // all lanes: norm of row r
        xn[s] = t;
    }

    float mk[4][4];
    #pragma unroll
    for (int s = 0; s < 4; ++s)
        #pragma unroll
        for (int i = 0; i < 4; ++i) mk[s][i] = INFINITY;

    const float inv = 1.0f / 512.0f;   // undo -1024 scale -> -2 x.e

#define COMPUTE(REG, C)                                                       \
    do {                                                                      \
        _Pragma("unroll")                                                     \
        for (int ts = 0; ts < 2; ++ts) {                                      \
            const int g = (kq * 16 + (C) * 2 + ts) * 16 + lr;   /* 10-bit */  \
            const float en = En1[g];                                          \
            f32x4 ac0 = {0,0,0,0}, ac1 = {0,0,0,0};                           \
            f32x4 ac2 = {0,0,0,0}, ac3 = {0,0,0,0};                           \
            _Pragma("unroll")                                                 \
            for (int kk = 0; kk < 8; ++kk) {                                  \
                const i64 b = REG[ts][kk >> 1][kk & 1];                       \
                ac0 = MFMA8(a[0][kk], b, ac0, 0, 0, 0);                       \
                ac1 = MFMA8(a[1][kk], b, ac1, 0, 0, 0);                       \
                ac2 = MFMA8(a[2][kk], b, ac2, 0, 0, 0);                       \
                ac3 = MFMA8(a[3][kk], b, ac3, 0, 0, 0);                       \
            }                                                                 \
            _Pragma("unroll")                                                 \
            for (int i = 0; i < 4; ++i) {                                     \
                float s0 = fmaf(ac0[i], inv, en);   /* (0.37,1.7): >0 */      \
                float s1 = fmaf(ac1[i], inv, en);                             \
                float s2 = fmaf(ac2[i], inv, en);                             \
                float s3 = fmaf(ac3[i], inv, en);                             \
                mk[0][i] = fminf(mk[0][i],                                    \
                    __uint_as_float(__float_as_uint(s0) | (unsigned)g));      \
                mk[1][i] = fminf(mk[1][i],                                    \
                    __uint_as_float(__float_as_uint(s1) | (unsigned)g));      \
                mk[2][i] = fminf(mk[2][i],                                    \
                    __uint_as_float(__float_as_uint(s2) | (unsigned)g));      \
                mk[3][i] = fminf(mk[3][i],                                    \
                    __uint_as_float(__float_as_uint(s3) | (unsigned)g));      \
            }                                                                 \
        }                                                                     \
    } while (0)

    // ---- barrier-free sweep: even/odd software pipeline, 8 chunks
    COMPUTE(bA, 0);  LOADC(bA, 2);
    COMPUTE(bB, 1);  LOADC(bB, 3);
    COMPUTE(bA, 2);  LOADC(bA, 4);
    COMPUTE(bB, 3);  LOADC(bB, 5);
    COMPUTE(bA, 4);  LOADC(bA, 6);
    COMPUTE(bB, 5);  LOADC(bB, 7);
    COMPUTE(bA, 6);
    COMPUTE(bB, 7);
#undef COMPUTE
#undef LOADC

    // ---- reduce keys over the 16 code-lanes (pure fminf butterfly)
    #pragma unroll
    for (int off = 1; off <= 8; off <<= 1)
        #pragma unroll
        for (int s = 0; s < 4; ++s)
            #pragma unroll
            for (int i = 0; i < 4; ++i)
                mk[s][i] = fminf(mk[s][i], __shfl_xor(mk[s][i], off, 64));

    // lanes lr==0 hold keys for rows s*16 + lk*4 + i
    if (lr == 0) {
        #pragma unroll
        for (int s = 0; s < 4; ++s)
            #pragma unroll
            for (int i = 0; i < 4; ++i)
                fk[kq][s * 16 + lk * 4 + i] = mk[s][i];
    }
    if (kq == 0 && l < 16) {
        #pragma unroll
        for (int s = 0; s < 4; ++s) fxn[s * 16 + l] = xn[s];
    }
    __syncthreads();

    // ---- merge kq quarters + gather E[idx] -> outq (wave: rows [kq*16,+16))
    #pragma unroll 4
    for (int rr = 0; rr < 16; ++rr) {
        const int r = kq * 16 + rr;
        const float key = fminf(fminf(fk[0][r], fk[1][r]),
                                fminf(fk[2][r], fk[3][r]));
        const int idx = (int)(__float_as_uint(key) & 1023u);
        const float4 qv = *reinterpret_cast<const float4*>(
            E + (size_t)idx * D_DIM + l * 4);
        *reinterpret_cast<float4*>(outq + (size_t)(brow + r) * D_DIM + l * 4) = qv;
    }

    // ---- loss partial: wave 0 sums (minval + xnorm) over the 64 rows
    if (kq == 0) {
        float v = 0.0f;
        if (l < BLOCK_ROWS) {
            const float key = fminf(fminf(fk[0][l], fk[1][l]),
                                    fminf(fk[2][l], fk[3][l]));
            const unsigned u = __float_as_uint(key);
            v = __uint_as_float(u & ~1023u) - 1.0f + fxn[l];
        }
        #pragma unroll
        for (int off = 32; off; off >>= 1) v += __shfl_xor(v, off, 64);
        if (l == 0) lpart[blockIdx.x] = v;
    }
}

// ---------------------------------------------------------------- finalize
// deterministic fold of 512 block partials -> vq_loss scalar
__global__ __launch_bounds__(256) void vq_finalize(const float* __restrict__ partials,
                                                   float* __restrict__ out_loss) {
    __shared__ float s[256];
    int t = threadIdx.x;
    s[t] = partials[t] + partials[t + 256];
    __syncthreads();
    #pragma unroll
    for (int off = 128; off; off >>= 1) {
        if (t < off) s[t] += s[t + off];
        __syncthreads();
    }
    if (t == 0)
        out_loss[0] = s[0] * (1.25f / (float)((size_t)N_ROWS * D_DIM));
}

// ---------------------------------------------------------------- launch
extern "C" void kernel_launch(void* const* d_in, const int* in_sizes, int n_in,
                              void* d_out, int out_size, void* d_ws, size_t ws_size,
                              hipStream_t stream) {
    const float* X = (const float*)d_in[0];   // latents  [32768, 256] f32
    const float* E = (const float*)d_in[1];   // codebook [1024, 256]  f32
    float* out = (float*)d_out;               // 8388608 quantized + 1 loss

    float* enorm1 = (float*)d_ws;                         // 1024 f32 (= 1+|e|^2)
    float* lpart  = enorm1 + K_CODES;                     // 512 f32 (1024 slot)
    i64*   Eb8    = (i64*)(lpart + 1024);                 // 256 KB fp8 frags

    vq_prep    <<<256,  256, 0, stream>>>(E, enorm1, Eb8);
    vq_main    <<<NBLK, 256, 0, stream>>>(X, E, enorm1, Eb8, out, lpart);
    vq_finalize<<<1,    256, 0, stream>>>(lpart, out + (size_t)N_ROWS * D_DIM);
}

// Round 20
// 35.414 us; speedup vs baseline: 1.0001x; 1.0001x over previous
//
#include <hip/hip_runtime.h>
#include <hip/hip_bf16.h>

#define D_DIM 256
#define K_CODES 1024
#define N_ROWS (32 * 1024)
#define BLOCK_ROWS 32                 // rows per block (shared by 4 kq waves)
#define NBLK (N_ROWS / BLOCK_ROWS)    // 1024 blocks -> 4/CU total, 3 resident

typedef __attribute__((ext_vector_type(4))) float f32x4;
typedef __attribute__((ext_vector_type(2))) long i64x2;
typedef long i64;

#define MFMA8 __builtin_amdgcn_mfma_f32_16x16x32_fp8_fp8
#define CVT8 __builtin_amdgcn_cvt_pk_fp8_f32

static __device__ __forceinline__ void gload_lds16(const void* g, void* s) {
    __builtin_amdgcn_global_load_lds(
        (const __attribute__((address_space(1))) void*)g,
        (__attribute__((address_space(3))) void*)s, 16, 0, 0);
}

static __device__ __forceinline__ i64 pack_fp8x8(float4 p, float4 q, float S) {
    int w0 = CVT8(p.x * S, p.y * S, 0, false);
    w0     = CVT8(p.z * S, p.w * S, w0, true);
    int w1 = CVT8(q.x * S, q.y * S, 0, false);
    w1     = CVT8(q.z * S, q.w * S, w1, true);
    return ((i64)(unsigned)w1 << 32) | (unsigned)w0;
}

// ---------------------------------------------------------------- prep
// (a) enorm1[k] = 1 + ||E[k]||^2 (keeps min-keys positive);
// (b) Eb8 = fp8(-1024*E), B-frag order, kk-PAIRED:
//     i64 idx(t16,kk,l) = t16*512 + (kk>>1)*128 + l*2 + (kk&1)
__global__ __launch_bounds__(256) void vq_prep(const float* __restrict__ E,
                                               float* __restrict__ enorm1,
                                               i64* __restrict__ Eb8) {
    int wave = threadIdx.x >> 6;
    int lane = threadIdx.x & 63;
    int k = blockIdx.x * 4 + wave;               // [0,1024)
    const float4 v = *reinterpret_cast<const float4*>(E + k * D_DIM + lane * 4);
    float s = v.x * v.x + v.y * v.y + v.z * v.z + v.w * v.w;
    #pragma unroll
    for (int off = 32; off; off >>= 1) s += __shfl_xor(s, off, 64);
    if (lane == 0) enorm1[k] = 1.0f + s;

    if (blockIdx.x < 128) {
        int g = blockIdx.x * 256 + threadIdx.x;  // [0, 32768)
        int t = g >> 9;
        int kk = (g >> 6) & 7;
        int l = g & 63;
        int code = t * 16 + (l & 15);
        int d0 = kk * 32 + ((l >> 4) << 3);
        const float* src = E + (size_t)code * D_DIM + d0;
        float4 v0 = *reinterpret_cast<const float4*>(src);
        float4 v1 = *reinterpret_cast<const float4*>(src + 4);
        Eb8[t * 512 + ((kk >> 1) << 7) + l * 2 + (kk & 1)] =
            pack_fp8x8(v0, v1, -1024.0f);
    }
}

// ---------------------------------------------------------------- main
// 1024 blocks of 32 rows (3 resident/CU + streaming 4th -> phases of
// different blocks pipeline: one block's X-DMA overlaps another's MFMA
// and a third's output writes). Wave kq: all 32 rows (2 MFMA rowsets)
// x codes [kq*256,+256) in 8 chunks of 32 codes loaded DIRECTLY to
// registers (named bA/bB even/odd pipeline). NO barriers in the sweep.
// Packed-key argmin; 4-way kq merge; fused gather epilogue; loss via
// |x-q|^2 = minval + |x|^2.
__global__ __launch_bounds__(256, 3) void vq_main(const float* __restrict__ X,
                                                  const float* __restrict__ E,
                                                  const float* __restrict__ enorm1,
                                                  const i64* __restrict__ Eb8,
                                                  float* __restrict__ outq,
                                                  float* __restrict__ lpart) {
    __shared__ i64   Xs[4096];         // 32 KB: 32 rows x 1KB
    __shared__ float En1[1024];        // 4 KB
    __shared__ float fk[4][BLOCK_ROWS];
    __shared__ float fxn[BLOCK_ROWS];

    const int tid = threadIdx.x;
    const int kq  = tid >> 6;     // wave = code quarter
    const int l   = tid & 63;
    const int lr  = l & 15;
    const int lk  = l >> 4;
    const int brow = blockIdx.x * BLOCK_ROWS;

    // ---- stage X coalesced (wave kq stages rows [kq*8,+8)) + En quarter
    #pragma unroll
    for (int rr = 0; rr < 8; ++rr) {
        const int r = kq * 8 + rr;
        gload_lds16(X + (size_t)(brow + r) * D_DIM + (l ^ (r & 7)) * 4,
                    &Xs[r * 128]);
    }
    gload_lds16(enorm1 + kq * 256 + l * 4, &En1[kq * 256]);
    __syncthreads();   // drains vmcnt: all 32 rows + En landed

    // ---- B chunk loads (32 codes = 2 16-code tiles) into named registers
    i64x2 bA[2][4], bB[2][4];
#define LOADC(REG, C)                                                         \
    do {                                                                      \
        const i64* tb = Eb8 + ((size_t)kq * 16 + (C) * 2) * 512;              \
        _Pragma("unroll")                                                     \
        for (int p = 0; p < 4; ++p) {                                         \
            REG[0][p] = *reinterpret_cast<const i64x2*>(tb + p * 128 + l * 2);\
            REG[1][p] = *reinterpret_cast<const i64x2*>(tb + 512 + p * 128 + l * 2); \
        }                                                                     \
    } while (0)

    LOADC(bA, 0);      // in flight under the pack phase
    LOADC(bB, 1);

    // ---- pack all 32 rows -> fp8 A-frags (2 rowsets) + row norms
    const float* Xf = reinterpret_cast<const float*>(Xs);
    i64   a[2][8];
    float xn[2];
    #pragma unroll
    for (int s = 0; s < 2; ++s) {
        const int r = s * 16 + lr;
        float t = 0.0f;
        #pragma unroll
        for (int kk = 0; kk < 8; ++kk) {
            const int c0 = (kk * 8 + lk * 2) ^ (r & 7);
            const int c1 = (kk * 8 + lk * 2 + 1) ^ (r & 7);
            float4 p = *reinterpret_cast<const float4*>(&Xf[r * 256 + c0 * 4]);
            float4 q = *reinterpret_cast<const float4*>(&Xf[r * 256 + c1 * 4]);
            t += p.x * p.x + p.y * p.y + p.z * p.z + p.w * p.w
               + q.x * q.x + q.y * q.y + q.z * q.z + q.w * q.w;
            a[s][kk] = pack_fp8x8(p, q, 1.0f);
        }
        t += __shfl_xor(t, 16, 64);
        t += __shfl_xor(t, 32, 64);   // all lanes: norm of row r
        xn[s] = t;
    }

    float mk[2][4];
    #pragma unroll
    for (int s = 0; s < 2; ++s)
        #pragma unroll
        for (int i = 0; i < 4; ++i) mk[s][i] = INFINITY;

    const float inv = 1.0f / 512.0f;   // undo -1024 scale -> -2 x.e

#define COMPUTE(REG, C)                                                       \
    do {                                                                      \
        _Pragma("unroll")                                                     \
        for (int ts = 0; ts < 2; ++ts) {                                      \
            const int g = (kq * 16 + (C) * 2 + ts) * 16 + lr;   /* 10-bit */  \
            const float en = En1[g];                                          \
            f32x4 ac0 = {0,0,0,0}, ac1 = {0,0,0,0};                           \
            _Pragma("unroll")                                                 \
            for (int kk = 0; kk < 8; ++kk) {                                  \
                const i64 b = REG[ts][kk >> 1][kk & 1];                       \
                ac0 = MFMA8(a[0][kk], b, ac0, 0, 0, 0);                       \
                ac1 = MFMA8(a[1][kk], b, ac1, 0, 0, 0);                       \
            }                                                                 \
            _Pragma("unroll")                                                 \
            for (int i = 0; i < 4; ++i) {                                     \
                float s0 = fmaf(ac0[i], inv, en);   /* (0.37,1.7): >0 */      \
                float s1 = fmaf(ac1[i], inv, en);                             \
                mk[0][i] = fminf(mk[0][i],                                    \
                    __uint_as_float(__float_as_uint(s0) | (unsigned)g));      \
                mk[1][i] = fminf(mk[1][i],                                    \
                    __uint_as_float(__float_as_uint(s1) | (unsigned)g));      \
            }                                                                 \
        }                                                                     \
    } while (0)

    // ---- barrier-free sweep: even/odd software pipeline, 8 chunks
    COMPUTE(bA, 0);  LOADC(bA, 2);
    COMPUTE(bB, 1);  LOADC(bB, 3);
    COMPUTE(bA, 2);  LOADC(bA, 4);
    COMPUTE(bB, 3);  LOADC(bB, 5);
    COMPUTE(bA, 4);  LOADC(bA, 6);
    COMPUTE(bB, 5);  LOADC(bB, 7);
    COMPUTE(bA, 6);
    COMPUTE(bB, 7);
#undef COMPUTE
#undef LOADC

    // ---- reduce keys over the 16 code-lanes (pure fminf butterfly)
    #pragma unroll
    for (int off = 1; off <= 8; off <<= 1)
        #pragma unroll
        for (int s = 0; s < 2; ++s)
            #pragma unroll
            for (int i = 0; i < 4; ++i)
                mk[s][i] = fminf(mk[s][i], __shfl_xor(mk[s][i], off, 64));

    // lanes lr==0 hold keys for rows s*16 + lk*4 + i
    if (lr == 0) {
        #pragma unroll
        for (int s = 0; s < 2; ++s)
            #pragma unroll
            for (int i = 0; i < 4; ++i)
                fk[kq][s * 16 + lk * 4 + i] = mk[s][i];
    }
    if (kq == 0 && l < 16) {
        fxn[l]      = xn[0];
        fxn[16 + l] = xn[1];
    }
    __syncthreads();

    // ---- merge kq quarters + gather E[idx] -> outq (wave: rows [kq*8,+8))
    #pragma unroll
    for (int rr = 0; rr < 8; ++rr) {
        const int r = kq * 8 + rr;
        const float key = fminf(fminf(fk[0][r], fk[1][r]),
                                fminf(fk[2][r], fk[3][r]));
        const int idx = (int)(__float_as_uint(key) & 1023u);
        const float4 qv = *reinterpret_cast<const float4*>(
            E + (size_t)idx * D_DIM + l * 4);
        *reinterpret_cast<float4*>(outq + (size_t)(brow + r) * D_DIM + l * 4) = qv;
    }

    // ---- loss partial: wave 0 sums (minval + xnorm) over the 32 rows
    if (kq == 0) {
        float v = 0.0f;
        if (l < BLOCK_ROWS) {
            const float key = fminf(fminf(fk[0][l], fk[1][l]),
                                    fminf(fk[2][l], fk[3][l]));
            const unsigned u = __float_as_uint(key);
            v = __uint_as_float(u & ~1023u) - 1.0f + fxn[l];
        }
        #pragma unroll
        for (int off = 32; off; off >>= 1) v += __shfl_xor(v, off, 64);
        if (l == 0) lpart[blockIdx.x] = v;
    }
}

// ---------------------------------------------------------------- finalize
// deterministic fold of 1024 block partials -> vq_loss scalar
__global__ __launch_bounds__(256) void vq_finalize(const float* __restrict__ partials,
                                                   float* __restrict__ out_loss) {
    __shared__ float s[256];
    int t = threadIdx.x;
    s[t] = partials[t] + partials[t + 256] + partials[t + 512] + partials[t + 768];
    __syncthreads();
    #pragma unroll
    for (int off = 128; off; off >>= 1) {
        if (t < off) s[t] += s[t + off];
        __syncthreads();
    }
    if (t == 0)
        out_loss[0] = s[0] * (1.25f / (float)((size_t)N_ROWS * D_DIM));
}

// ---------------------------------------------------------------- launch
extern "C" void kernel_launch(void* const* d_in, const int* in_sizes, int n_in,
                              void* d_out, int out_size, void* d_ws, size_t ws_size,
                              hipStream_t stream) {
    const float* X = (const float*)d_in[0];   // latents  [32768, 256] f32
    const float* E = (const float*)d_in[1];   // codebook [1024, 256]  f32
    float* out = (float*)d_out;               // 8388608 quantized + 1 loss

    float* enorm1 = (float*)d_ws;                         // 1024 f32 (= 1+|e|^2)
    float* lpart  = enorm1 + K_CODES;                     // 1024 f32
    i64*   Eb8    = (i64*)(lpart + 1024);                 // 256 KB fp8 frags

    vq_prep    <<<256,  256, 0, stream>>>(E, enorm1, Eb8);
    vq_main    <<<NBLK, 256, 0, stream>>>(X, E, enorm1, Eb8, out, lpart);
    vq_finalize<<<1,    256, 0, stream>>>(lpart, out + (size_t)N_ROWS * D_DIM);
}